// Round 4
// baseline (900.816 us; speedup 1.0000x reference)
//
#include <hip/hip_runtime.h>
#include <hip/hip_bf16.h>

// SA_fusion: B=4, C=512, H=W=64 (HW=4096), fp32 in/out.
// R4: occupancy-directed. Tiered on ws_size (constant per session -> capture
// safe): tier1 batches scores/softmax/PV across all 4 batches (scores grid
// 4096 blocks = 16/CU vs 4/CU), tier2 batches PV only, tier3 = R3 layout.
// q+k convs merged into one z=8 launch (QK flag: sel=z>>2 strides A, B, bias, C).

typedef __bf16 bf16_t;
typedef __bf16 bf16x8 __attribute__((ext_vector_type(8)));
typedef float f32x4 __attribute__((ext_vector_type(4)));

#define C_DIM 512
#define HW_DIM 4096
#define NBATCH 4
#define CHW (512L * 4096L)
#define HWHW (4096L * 4096L)

__device__ inline f32x4 mfma_bf16(bf16x8 a, bf16x8 b, f32x4 c) {
    return __builtin_amdgcn_mfma_f32_16x16x32_bf16(a, b, c, 0, 0, 0);
}

__device__ inline void g2l16(const bf16_t* g, bf16_t* l) {
    auto gp = (const __attribute__((address_space(1))) uint32_t*)(uintptr_t)g;
    auto lp = (__attribute__((address_space(3))) uint32_t*)(uint32_t)(uintptr_t)l;
    __builtin_amdgcn_global_load_lds(gp, lp, 16, 0, 0);
}

// ---------------- stats ------------------------------------------------------
__global__ __launch_bounds__(256) void stats_kernel(
    const float* __restrict__ xc, const float* __restrict__ xs,
    float* __restrict__ meanc, float* __restrict__ rstdc,
    float* __restrict__ means, float* __restrict__ rstds)
{
    int id = blockIdx.x;
    int bc = id & 2047;
    const float4* x = (const float4*)((id < 2048 ? xc : xs) + (size_t)bc * HW_DIM);
    int tid = threadIdx.x;
    float s = 0.f, ss = 0.f;
#pragma unroll
    for (int i = 0; i < 4; i++) {
        float4 v = x[tid + (i << 8)];
        s += v.x + v.y + v.z + v.w;
        ss += v.x * v.x + v.y * v.y + v.z * v.z + v.w * v.w;
    }
#pragma unroll
    for (int o = 32; o; o >>= 1) { s += __shfl_down(s, o); ss += __shfl_down(ss, o); }
    __shared__ float red[8];
    if ((tid & 63) == 0) { red[(tid >> 6) * 2] = s; red[(tid >> 6) * 2 + 1] = ss; }
    __syncthreads();
    if (tid == 0) {
        s  = red[0] + red[2] + red[4] + red[6];
        ss = red[1] + red[3] + red[5] + red[7];
        float mean = s * (1.0f / 4096.0f);
        float var  = (ss - 4096.0f * mean * mean) * (1.0f / 4095.0f);
        float rstd = rsqrtf(var + 1e-5f);
        if (id < 2048) { meanc[bc] = mean; rstdc[bc] = rstd; }
        else           { means[bc] = mean; rstds[bc] = rstd; }
    }
}

// ---------------- weight pack + bias copy ------------------------------------
__global__ __launch_bounds__(256) void pack_w4_kernel(
    const float* __restrict__ w0, const float* __restrict__ w1,
    const float* __restrict__ w2, const float* __restrict__ w3,
    bf16_t* __restrict__ h0, bf16_t* __restrict__ h1,
    bf16_t* __restrict__ h2, bf16_t* __restrict__ h3,
    bf16_t* __restrict__ l0, bf16_t* __restrict__ l1,
    bf16_t* __restrict__ l2, bf16_t* __restrict__ l3,
    const float* __restrict__ bb0, const float* __restrict__ bb1,
    const float* __restrict__ bb2, const float* __restrict__ bb3,
    float* __restrict__ biasws)
{
    int which = blockIdx.y;
    const float* w = which == 0 ? w0 : which == 1 ? w1 : which == 2 ? w2 : w3;
    bf16_t* h = which == 0 ? h0 : which == 1 ? h1 : which == 2 ? h2 : h3;
    bf16_t* l = which == 0 ? l0 : which == 1 ? l1 : which == 2 ? l2 : l3;
    const float* bs = which == 0 ? bb0 : which == 1 ? bb1 : which == 2 ? bb2 : bb3;
    int i = blockIdx.x * 256 + threadIdx.x;
    float v = w[i];
    bf16_t hh = (bf16_t)v;
    h[i] = hh;
    l[i] = (bf16_t)(v - (float)hh);
    if (i < C_DIM) biasws[which * C_DIM + i] = bs[i];
}

// ---------------- input pack -------------------------------------------------
__global__ __launch_bounds__(256) void pack_T_kernel(
    const float* __restrict__ xc, const float* __restrict__ xs,
    const float* __restrict__ meanc, const float* __restrict__ rstdc,
    const float* __restrict__ means, const float* __restrict__ rstds,
    bf16_t* __restrict__ ch, bf16_t* __restrict__ cl,
    bf16_t* __restrict__ sh, bf16_t* __restrict__ sl,
    bf16_t* __restrict__ sraw)
{
    __shared__ float tile[32][33];
    int z = blockIdx.z;
    int b = z & 3, src = z >> 2;
    const float* x    = (src == 0) ? xc : xs;
    const float* mean = (src == 0) ? meanc : means;
    const float* rstd = (src == 0) ? rstdc : rstds;
    bf16_t* oh = (src == 0) ? ch : (src == 1) ? sh : sraw;
    bf16_t* ol = (src == 0) ? cl : sl;
    bool norm = (src < 2);

    int c0 = blockIdx.y * 32, p0 = blockIdx.x * 32;
    int tp = threadIdx.x & 31, tc8 = threadIdx.x >> 5;
    const float* xb = x + ((size_t)b * C_DIM + c0) * HW_DIM + p0;
#pragma unroll
    for (int it = 0; it < 4; it++) {
        int c = tc8 + it * 8;
        float v = xb[(size_t)c * HW_DIM + tp];
        if (norm) {
            float m = mean[b * C_DIM + c0 + c];
            float r = rstd[b * C_DIM + c0 + c];
            v = (v - m) * r;
        }
        tile[c][tp] = v;
    }
    __syncthreads();
    int wc = threadIdx.x & 31, wp8 = threadIdx.x >> 5;
    bf16_t* ohb = oh + ((size_t)b * HW_DIM + p0) * C_DIM + c0;
#pragma unroll
    for (int it = 0; it < 4; it++) {
        int p = wp8 + it * 8;
        float v = tile[wc][p];
        bf16_t h = (bf16_t)v;
        ohb[(size_t)p * C_DIM + wc] = h;
        if (norm) {
            bf16_t lo = (bf16_t)(v - (float)h);
            ol[((size_t)b * HW_DIM + p0 + p) * C_DIM + c0 + wc] = lo;
        }
    }
}

// ---------------- row softmax (batched via blockIdx.y) -----------------------
__global__ __launch_bounds__(256) void softmax_rows(
    const float* __restrict__ S, bf16_t* __restrict__ P, long sS, long sP)
{
    int row = blockIdx.x;
    int tid = threadIdx.x;
    int wave = tid >> 6, lane = tid & 63;
    const float4* sr = (const float4*)(S + (size_t)blockIdx.y * sS + (size_t)row * HW_DIM);
    float4 v[4];
    float mx = -3.4e38f;
#pragma unroll
    for (int i = 0; i < 4; i++) {
        v[i] = sr[tid + (i << 8)];
        mx = fmaxf(mx, fmaxf(fmaxf(v[i].x, v[i].y), fmaxf(v[i].z, v[i].w)));
    }
#pragma unroll
    for (int o = 32; o; o >>= 1) mx = fmaxf(mx, __shfl_down(mx, o));
    __shared__ float red[4];
    if (lane == 0) red[wave] = mx;
    __syncthreads();
    mx = fmaxf(fmaxf(red[0], red[1]), fmaxf(red[2], red[3]));
    float sum = 0.f;
#pragma unroll
    for (int i = 0; i < 4; i++) {
        v[i].x = __expf(v[i].x - mx); v[i].y = __expf(v[i].y - mx);
        v[i].z = __expf(v[i].z - mx); v[i].w = __expf(v[i].w - mx);
        sum += v[i].x + v[i].y + v[i].z + v[i].w;
    }
#pragma unroll
    for (int o = 32; o; o >>= 1) sum += __shfl_down(sum, o);
    __syncthreads();
    if (lane == 0) red[wave] = sum;
    __syncthreads();
    sum = red[0] + red[1] + red[2] + red[3];
    float inv = 1.0f / sum;
    uint2* pr = (uint2*)(P + (size_t)blockIdx.y * sP + (size_t)row * HW_DIM);
#pragma unroll
    for (int i = 0; i < 4; i++) {
        union { uint2 u; bf16_t h[4]; } o;
        o.h[0] = (bf16_t)(v[i].x * inv); o.h[1] = (bf16_t)(v[i].y * inv);
        o.h[2] = (bf16_t)(v[i].z * inv); o.h[3] = (bf16_t)(v[i].w * inv);
        pr[tid + (i << 8)] = o.u;
    }
}

// ---------------- NT GEMM ----------------------------------------------------
// QK: z encodes (sel=z>>2, batch=z&3); sel strides A (sAw), B (sBw),
// bias (+sel*C_DIM), C (sCw).
template<int WM, int WN, int EPI, bool SPLIT, bool QK>
__global__ __launch_bounds__(256) void gemm_nt(
    const bf16_t* __restrict__ Ah, const bf16_t* __restrict__ Al,
    const bf16_t* __restrict__ Bh, const bf16_t* __restrict__ Bl,
    void* __restrict__ Cout0, void* __restrict__ Cout1,
    const float* __restrict__ bias, const float* __restrict__ resid,
    int K, int ldc,
    long sAz, long sBz, long sCz, long sRz, long sAw, long sBw, long sCw)
{
    constexpr int BM = 2 * WM * 16;
    constexpr int BN = 2 * WN * 16;
    constexpr int BK = 32;
    constexpr int NT = (SPLIT ? 2 : 1);
    __shared__ __align__(16) bf16_t smem[NT * (BM + BN) * BK];
    bf16_t* sAh = smem;
    bf16_t* sAl = smem + BM * BK;
    bf16_t* sBh = smem + NT * BM * BK;
    bf16_t* sBl = sBh + BN * BK;

    const int tid  = threadIdx.x;
    const int wave = tid >> 6, lane = tid & 63;
    const int wm = (wave >> 1) * (WM * 16);
    const int wn = (wave & 1) * (WN * 16);
    const int fr = lane & 15;
    const int fk = (lane >> 4) * 8;
    const int srow = lane >> 2;
    const int scol = (lane & 3) * 8;

    const long mBlock = (long)blockIdx.y * BM;
    const long nBlock = (long)blockIdx.x * BN;
    const int zz = blockIdx.z;
    const int z   = QK ? (zz & 3) : zz;
    const int sel = QK ? (zz >> 2) : 0;
    const bf16_t* Az  = Ah + (size_t)z * sAz + (size_t)sel * sAw;
    const bf16_t* Bz  = Bh + (size_t)z * sBz + (size_t)sel * sBw;
    const bf16_t* Azl = SPLIT ? (Al + (size_t)z * sAz + (size_t)sel * sAw) : nullptr;
    const bf16_t* Bzl = SPLIT ? (Bl + (size_t)z * sBz + (size_t)sel * sBw) : nullptr;
    const float* biasp = bias ? (bias + (QK ? sel * C_DIM : 0)) : nullptr;

    const bf16_t* gA  = Az + (size_t)(mBlock + srow) * K + scol;
    const bf16_t* gB  = Bz + (size_t)(nBlock + srow) * K + scol;
    const bf16_t* gAl = SPLIT ? (Azl + (size_t)(mBlock + srow) * K + scol) : nullptr;
    const bf16_t* gBl = SPLIT ? (Bzl + (size_t)(nBlock + srow) * K + scol) : nullptr;

    f32x4 acc[WM][WN];
#pragma unroll
    for (int i = 0; i < WM; i++)
#pragma unroll
        for (int j = 0; j < WN; j++)
            acc[i][j] = (f32x4){0.f, 0.f, 0.f, 0.f};

    for (int k0 = 0; k0 < K; k0 += BK) {
        __syncthreads();
#pragma unroll
        for (int s = 0; s < BM / 16; s += 4) {
            int seg = s + wave;
            g2l16(gA + (size_t)seg * 16 * K + k0, sAh + seg * 512);
            if (SPLIT)
                g2l16(gAl + (size_t)seg * 16 * K + k0, sAl + seg * 512);
        }
#pragma unroll
        for (int s = 0; s < BN / 16; s += 4) {
            int seg = s + wave;
            g2l16(gB + (size_t)seg * 16 * K + k0, sBh + seg * 512);
            if (SPLIT)
                g2l16(gBl + (size_t)seg * 16 * K + k0, sBl + seg * 512);
        }
        __syncthreads();

        bf16x8 ah[WM], bh[WN], alo[WM], blo[WN];
#pragma unroll
        for (int i = 0; i < WM; i++) {
            ah[i] = *reinterpret_cast<const bf16x8*>(sAh + (wm + i * 16 + fr) * BK + fk);
            if (SPLIT)
                alo[i] = *reinterpret_cast<const bf16x8*>(sAl + (wm + i * 16 + fr) * BK + fk);
        }
#pragma unroll
        for (int j = 0; j < WN; j++) {
            bh[j] = *reinterpret_cast<const bf16x8*>(sBh + (wn + j * 16 + fr) * BK + fk);
            if (SPLIT)
                blo[j] = *reinterpret_cast<const bf16x8*>(sBl + (wn + j * 16 + fr) * BK + fk);
        }
#pragma unroll
        for (int i = 0; i < WM; i++)
#pragma unroll
            for (int j = 0; j < WN; j++) {
                acc[i][j] = mfma_bf16(ah[i], bh[j], acc[i][j]);
                if (SPLIT) {
                    acc[i][j] = mfma_bf16(ah[i], blo[j], acc[i][j]);
                    acc[i][j] = mfma_bf16(alo[i], bh[j], acc[i][j]);
                }
            }
    }

    const int col  = lane & 15;
    const int rowq = (lane >> 4) * 4;
    const size_t cbase = (size_t)z * sCz + (size_t)sel * sCw;
#pragma unroll
    for (int i = 0; i < WM; i++) {
        const long mb = mBlock + wm + i * 16 + rowq;
        float bv[4];
#pragma unroll
        for (int r = 0; r < 4; r++) bv[r] = biasp ? biasp[mb + r] : 0.0f;
#pragma unroll
        for (int j = 0; j < WN; j++) {
            const long n = nBlock + wn + j * 16 + col;
            float v[4];
#pragma unroll
            for (int r = 0; r < 4; r++) v[r] = acc[i][j][r] + bv[r];
            if constexpr (EPI == 0) {
                float* O = (float*)Cout0 + cbase;
                const float* R = resid ? (resid + (size_t)z * sRz) : nullptr;
#pragma unroll
                for (int r = 0; r < 4; r++) {
                    size_t off = (size_t)(mb + r) * ldc + n;
                    O[off] = v[r] + (R ? R[off] : 0.0f);
                }
            } else if constexpr (EPI == 1) {
                bf16_t* O = (bf16_t*)Cout0 + cbase;
#pragma unroll
                for (int r = 0; r < 4; r++) O[(size_t)(mb + r) * ldc + n] = (bf16_t)v[r];
            } else if constexpr (EPI == 2) {
                alignas(8) bf16_t h[4], l[4];
#pragma unroll
                for (int r = 0; r < 4; r++) {
                    h[r] = (bf16_t)v[r];
                    l[r] = (bf16_t)(v[r] - (float)h[r]);
                }
                size_t offo = cbase + (size_t)n * ldc + mb;
                *reinterpret_cast<uint2*>((bf16_t*)Cout0 + offo) = *reinterpret_cast<uint2*>(h);
                *reinterpret_cast<uint2*>((bf16_t*)Cout1 + offo) = *reinterpret_cast<uint2*>(l);
            } else {
                alignas(8) bf16_t h[4];
#pragma unroll
                for (int r = 0; r < 4; r++) h[r] = (bf16_t)v[r];
                size_t offo = cbase + (size_t)n * ldc + mb;
                *reinterpret_cast<uint2*>((bf16_t*)Cout0 + offo) = *reinterpret_cast<uint2*>(h);
            }
        }
    }
}

// ---------------------------------------------------------------------------
extern "C" void kernel_launch(void* const* d_in, const int* in_sizes, int n_in,
                              void* d_out, int out_size, void* d_ws, size_t ws_size,
                              hipStream_t stream)
{
    const float* x_fcc = (const float*)d_in[0];
    const float* x_fss = (const float*)d_in[1];
    const float* w1 = (const float*)d_in[2];
    const float* b1 = (const float*)d_in[3];
    const float* w2 = (const float*)d_in[4];
    const float* b2 = (const float*)d_in[5];
    const float* w3 = (const float*)d_in[6];
    const float* b3 = (const float*)d_in[7];
    const float* wrs = (const float*)d_in[8];
    const float* brs = (const float*)d_in[9];
    float* out = (float*)d_out;
    (void)n_in; (void)in_sizes; (void)out_size;

    const size_t MB = 1ull << 20;
    char* base = (char*)d_ws;
    size_t off = 0;
    auto take = [&](size_t bytes) -> char* {
        char* p = base + off;
        off += (bytes + 255) & ~(size_t)255;
        return p;
    };
    const size_t WB = (size_t)C_DIM * C_DIM * sizeof(bf16_t);   // 512 KB
    const size_t TB = (size_t)NBATCH * CHW * sizeof(bf16_t);    // 16 MB
    const long  TBe = NBATCH * CHW;                             // 8388608 elems

    float* meanc = (float*)take(2048 * 4);
    float* rstdc = (float*)take(2048 * 4);
    float* means = (float*)take(2048 * 4);
    float* rstds = (float*)take(2048 * 4);
    float* biasws = (float*)take(4 * C_DIM * 4);
    bf16_t* w1h = (bf16_t*)take(WB); bf16_t* w1l = (bf16_t*)take(WB);
    bf16_t* w2h = (bf16_t*)take(WB); bf16_t* w2l = (bf16_t*)take(WB);
    bf16_t* w3h = (bf16_t*)take(WB); bf16_t* w3l = (bf16_t*)take(WB);
    bf16_t* wrh = (bf16_t*)take(WB); bf16_t* wrl = (bf16_t*)take(WB);
    bf16_t* qTh = (bf16_t*)take(TB);
    bf16_t* qTl = (bf16_t*)take(TB);
    bf16_t* kTh = (bf16_t*)take(TB);
    bf16_t* kTl = (bf16_t*)take(TB);
    bf16_t* vh   = (bf16_t*)take(TB);
    bf16_t* frsT = (bf16_t*)take(TB);

    int tier = (ws_size >= 490 * MB) ? 1 : (ws_size >= 315 * MB) ? 2 : 3;

    // pack region: xcTh, xcTl, xsTh, xsTl, xsrT (sel-stride hi: xcTh->xsTh =
    // 2*TBe; lo: xcTl->xsTl = 2*TBe). S aliases region head after convs.
    size_t packBytes = 5 * TB;                              // 80 MB
    size_t sRegion = (tier == 1) ? (size_t)NBATCH * HWHW * 4 // 256 MB
                   : (tier == 2) ? packBytes
                   : 6 * TB;                                 // 96 MB (R3)
    char* packb = take(sRegion > packBytes ? sRegion : packBytes);
    bf16_t* xcTh = (bf16_t*)(packb);
    bf16_t* xcTl = (bf16_t*)(packb + TB);
    bf16_t* xsTh = (bf16_t*)(packb + 2 * TB);
    bf16_t* xsTl = (bf16_t*)(packb + 3 * TB);
    bf16_t* xsrT = (bf16_t*)(packb + 4 * TB);
    float*  Smat = (float*)(packb);
    bf16_t* Pmat;
    if (tier == 3) Pmat = (bf16_t*)(packb + 4 * TB);
    else           Pmat = (bf16_t*)take((size_t)NBATCH * HWHW * 2);  // 128 MB

    dim3 blk(256);

    stats_kernel<<<dim3(4096), blk, 0, stream>>>(x_fcc, x_fss, meanc, rstdc, means, rstds);
    pack_w4_kernel<<<dim3(1024, 4), blk, 0, stream>>>(
        w1, w2, w3, wrs, w1h, w2h, w3h, wrh, w1l, w2l, w3l, wrl,
        b1, b2, b3, brs, biasws);
    pack_T_kernel<<<dim3(128, 16, 12), blk, 0, stream>>>(
        x_fcc, x_fss, meanc, rstdc, means, rstds, xcTh, xcTl, xsTh, xsTl, xsrT);

    // q+k convs merged: sel 0 = (w1, content) -> q; sel 1 = (w2, style) -> k
    gemm_nt<4, 4, 2, true, true><<<dim3(32, 4, 8), blk, 0, stream>>>(
        w1h, w1l, xcTh, xcTl, qTh, qTl, biasws, nullptr, C_DIM, C_DIM,
        0L, CHW, CHW, 0L, 2L * C_DIM * C_DIM, 2L * TBe, 2L * TBe);
    gemm_nt<4, 4, 1, false, false><<<dim3(32, 4, 4), blk, 0, stream>>>(
        w3h, nullptr, xsrT, nullptr, vh, nullptr, biasws + 2 * C_DIM, nullptr,
        C_DIM, HW_DIM, 0L, CHW, CHW, 0L, 0L, 0L, 0L);

    if (tier == 1) {
        gemm_nt<4, 4, 0, true, false><<<dim3(32, 32, 4), blk, 0, stream>>>(
            qTh, qTl, kTh, kTl, Smat, nullptr, nullptr, nullptr,
            C_DIM, HW_DIM, CHW, CHW, HWHW, 0L, 0L, 0L, 0L);
        softmax_rows<<<dim3(4096, 4), blk, 0, stream>>>(Smat, Pmat, HWHW, HWHW);
        gemm_nt<2, 4, 3, false, false><<<dim3(32, 8, 4), blk, 0, stream>>>(
            vh, nullptr, Pmat, nullptr, frsT, nullptr, nullptr, nullptr,
            HW_DIM, C_DIM, CHW, HWHW, CHW, 0L, 0L, 0L, 0L);
    } else if (tier == 2) {
        for (int b = 0; b < NBATCH; b++) {
            gemm_nt<4, 4, 0, true, false><<<dim3(32, 32, 1), blk, 0, stream>>>(
                qTh + (size_t)b * CHW, qTl + (size_t)b * CHW,
                kTh + (size_t)b * CHW, kTl + (size_t)b * CHW,
                Smat, nullptr, nullptr, nullptr, C_DIM, HW_DIM,
                0L, 0L, 0L, 0L, 0L, 0L, 0L);
            softmax_rows<<<dim3(4096, 1), blk, 0, stream>>>(
                Smat, Pmat + (size_t)b * HWHW, 0L, 0L);
        }
        gemm_nt<2, 4, 3, false, false><<<dim3(32, 8, 4), blk, 0, stream>>>(
            vh, nullptr, Pmat, nullptr, frsT, nullptr, nullptr, nullptr,
            HW_DIM, C_DIM, CHW, HWHW, CHW, 0L, 0L, 0L, 0L);
    } else {
        for (int b = 0; b < NBATCH; b++) {
            gemm_nt<4, 4, 0, true, false><<<dim3(32, 32, 1), blk, 0, stream>>>(
                qTh + (size_t)b * CHW, qTl + (size_t)b * CHW,
                kTh + (size_t)b * CHW, kTl + (size_t)b * CHW,
                Smat, nullptr, nullptr, nullptr, C_DIM, HW_DIM,
                0L, 0L, 0L, 0L, 0L, 0L, 0L);
            softmax_rows<<<dim3(4096, 1), blk, 0, stream>>>(Smat, Pmat, 0L, 0L);
            gemm_nt<2, 4, 3, false, false><<<dim3(32, 8, 1), blk, 0, stream>>>(
                vh + (size_t)b * CHW, nullptr, Pmat, nullptr,
                frsT + (size_t)b * CHW, nullptr, nullptr, nullptr,
                HW_DIM, C_DIM, 0L, 0L, 0L, 0L, 0L, 0L, 0L);
        }
    }
    gemm_nt<4, 4, 0, false, false><<<dim3(32, 4, 4), blk, 0, stream>>>(
        wrh, nullptr, frsT, nullptr, out, nullptr, biasws + 3 * C_DIM, x_fcc,
        C_DIM, HW_DIM, 0L, CHW, CHW, CHW, 0L, 0L, 0L);
}

// Round 5
// 738.432 us; speedup vs baseline: 1.2199x; 1.2199x over previous
//
#include <hip/hip_runtime.h>
#include <hip/hip_bf16.h>

// SA_fusion: B=4, C=512, H=W=64 (HW=4096), fp32 in/out.
// R5: plain fp16 end-to-end (no hi/lo split). fp16 rounding (2^-11) keeps
// logit error ~0.02 -> absmax ~0.06 < 0.156 threshold, while cutting scores
// MFMA volume 3x and staging 2x vs the bf16-split design. Fixed ~162 MB
// workspace (no ws_size tiers). Per-batch S (64 MB fp32) / P (32 MB fp16)
// stay L3-hot between scores -> softmax -> PV.

typedef _Float16 f16_t;
typedef _Float16 f16x8 __attribute__((ext_vector_type(8)));
typedef float f32x4 __attribute__((ext_vector_type(4)));

#define C_DIM 512
#define HW_DIM 4096
#define NBATCH 4
#define CHW (512L * 4096L)
#define HWHW (4096L * 4096L)

__device__ inline f32x4 mfma_f16(f16x8 a, f16x8 b, f32x4 c) {
    return __builtin_amdgcn_mfma_f32_16x16x32_f16(a, b, c, 0, 0, 0);
}

// async 16B/lane global->LDS; lane i lands at base + i*16 (wave-uniform base).
__device__ inline void g2l16(const f16_t* g, f16_t* l) {
    auto gp = (const __attribute__((address_space(1))) uint32_t*)(uintptr_t)g;
    auto lp = (__attribute__((address_space(3))) uint32_t*)(uint32_t)(uintptr_t)l;
    __builtin_amdgcn_global_load_lds(gp, lp, 16, 0, 0);
}

// ---------------- stats: mean + rstd (unbiased var, ddof=1) per (b,c) --------
__global__ __launch_bounds__(256) void stats_kernel(
    const float* __restrict__ xc, const float* __restrict__ xs,
    float* __restrict__ meanc, float* __restrict__ rstdc,
    float* __restrict__ means, float* __restrict__ rstds)
{
    int id = blockIdx.x;
    int bc = id & 2047;
    const float4* x = (const float4*)((id < 2048 ? xc : xs) + (size_t)bc * HW_DIM);
    int tid = threadIdx.x;
    float s = 0.f, ss = 0.f;
#pragma unroll
    for (int i = 0; i < 4; i++) {
        float4 v = x[tid + (i << 8)];
        s += v.x + v.y + v.z + v.w;
        ss += v.x * v.x + v.y * v.y + v.z * v.z + v.w * v.w;
    }
#pragma unroll
    for (int o = 32; o; o >>= 1) { s += __shfl_down(s, o); ss += __shfl_down(ss, o); }
    __shared__ float red[8];
    if ((tid & 63) == 0) { red[(tid >> 6) * 2] = s; red[(tid >> 6) * 2 + 1] = ss; }
    __syncthreads();
    if (tid == 0) {
        s  = red[0] + red[2] + red[4] + red[6];
        ss = red[1] + red[3] + red[5] + red[7];
        float mean = s * (1.0f / 4096.0f);
        float var  = (ss - 4096.0f * mean * mean) * (1.0f / 4095.0f);
        float rstd = rsqrtf(var + 1e-5f);
        if (id < 2048) { meanc[bc] = mean; rstdc[bc] = rstd; }
        else           { means[bc] = mean; rstds[bc] = rstd; }
    }
}

// ---------------- weight pack: fp32 -> fp16 + bias copy ----------------------
__global__ __launch_bounds__(256) void pack_w4_kernel(
    const float* __restrict__ w0, const float* __restrict__ w1,
    const float* __restrict__ w2, const float* __restrict__ w3,
    f16_t* __restrict__ h0, f16_t* __restrict__ h1,
    f16_t* __restrict__ h2, f16_t* __restrict__ h3,
    const float* __restrict__ bb0, const float* __restrict__ bb1,
    const float* __restrict__ bb2, const float* __restrict__ bb3,
    float* __restrict__ biasws)
{
    int which = blockIdx.y;
    const float* w = which == 0 ? w0 : which == 1 ? w1 : which == 2 ? w2 : w3;
    f16_t* h = which == 0 ? h0 : which == 1 ? h1 : which == 2 ? h2 : h3;
    const float* bs = which == 0 ? bb0 : which == 1 ? bb1 : which == 2 ? bb2 : bb3;
    int i = blockIdx.x * 256 + threadIdx.x;
    h[i] = (f16_t)w[i];
    if (i < C_DIM) biasws[which * C_DIM + i] = bs[i];
}

// ---------------- input pack: (B,C,HW) fp32 -> (B,HW,C) fp16, opt norm -------
// z = b + 4*src; src 0: content norm, 1: style norm, 2: style raw
__global__ __launch_bounds__(256) void pack_T_kernel(
    const float* __restrict__ xc, const float* __restrict__ xs,
    const float* __restrict__ meanc, const float* __restrict__ rstdc,
    const float* __restrict__ means, const float* __restrict__ rstds,
    f16_t* __restrict__ ch, f16_t* __restrict__ sh, f16_t* __restrict__ sraw)
{
    __shared__ float tile[32][33];
    int z = blockIdx.z;
    int b = z & 3, src = z >> 2;
    const float* x    = (src == 0) ? xc : xs;
    const float* mean = (src == 0) ? meanc : means;
    const float* rstd = (src == 0) ? rstdc : rstds;
    f16_t* oh = (src == 0) ? ch : (src == 1) ? sh : sraw;
    bool norm = (src < 2);

    int c0 = blockIdx.y * 32, p0 = blockIdx.x * 32;
    int tp = threadIdx.x & 31, tc8 = threadIdx.x >> 5;
    const float* xb = x + ((size_t)b * C_DIM + c0) * HW_DIM + p0;
#pragma unroll
    for (int it = 0; it < 4; it++) {
        int c = tc8 + it * 8;
        float v = xb[(size_t)c * HW_DIM + tp];
        if (norm) {
            float m = mean[b * C_DIM + c0 + c];
            float r = rstd[b * C_DIM + c0 + c];
            v = (v - m) * r;
        }
        tile[c][tp] = v;
    }
    __syncthreads();
    int wc = threadIdx.x & 31, wp8 = threadIdx.x >> 5;
    f16_t* ohb = oh + ((size_t)b * HW_DIM + p0) * C_DIM + c0;
#pragma unroll
    for (int it = 0; it < 4; it++) {
        int p = wp8 + it * 8;
        ohb[(size_t)p * C_DIM + wc] = (f16_t)tile[wc][p];
    }
}

// ---------------- row softmax: S fp32 (4096x4096) -> P fp16, normalized ------
__global__ __launch_bounds__(256) void softmax_rows(
    const float* __restrict__ S, f16_t* __restrict__ P)
{
    int row = blockIdx.x;
    int tid = threadIdx.x;
    int wave = tid >> 6, lane = tid & 63;
    const float4* sr = (const float4*)(S + (size_t)row * HW_DIM);
    float4 v[4];
    float mx = -3.4e38f;
#pragma unroll
    for (int i = 0; i < 4; i++) {
        v[i] = sr[tid + (i << 8)];
        mx = fmaxf(mx, fmaxf(fmaxf(v[i].x, v[i].y), fmaxf(v[i].z, v[i].w)));
    }
#pragma unroll
    for (int o = 32; o; o >>= 1) mx = fmaxf(mx, __shfl_down(mx, o));
    __shared__ float red[4];
    if (lane == 0) red[wave] = mx;
    __syncthreads();
    mx = fmaxf(fmaxf(red[0], red[1]), fmaxf(red[2], red[3]));
    float sum = 0.f;
#pragma unroll
    for (int i = 0; i < 4; i++) {
        v[i].x = __expf(v[i].x - mx); v[i].y = __expf(v[i].y - mx);
        v[i].z = __expf(v[i].z - mx); v[i].w = __expf(v[i].w - mx);
        sum += v[i].x + v[i].y + v[i].z + v[i].w;
    }
#pragma unroll
    for (int o = 32; o; o >>= 1) sum += __shfl_down(sum, o);
    __syncthreads();
    if (lane == 0) red[wave] = sum;
    __syncthreads();
    sum = red[0] + red[1] + red[2] + red[3];
    float inv = 1.0f / sum;
    uint2* pr = (uint2*)(P + (size_t)row * HW_DIM);
#pragma unroll
    for (int i = 0; i < 4; i++) {
        union { uint2 u; f16_t h[4]; } o;
        o.h[0] = (f16_t)(v[i].x * inv); o.h[1] = (f16_t)(v[i].y * inv);
        o.h[2] = (f16_t)(v[i].z * inv); o.h[3] = (f16_t)(v[i].w * inv);
        pr[tid + (i << 8)] = o.u;
    }
}

// ---------------- NT GEMM: C[m][n] = sum_k A[m][k]*B[n][k] -------------------
// fp16, 16x16x32 MFMA, block=256 (2x2 waves), async global_load_lds staging,
// unpadded [row][32] LDS tiles (m97 structure).
// QK: z encodes (sel=z>>2, batch=z&3); sel strides A (sAw), B (sBw),
// bias (+sel*C_DIM), C (sCw).
// EPI: 0 fp32 [m][n] (+bias,+resid); 1 f16 [m][n] (+bias); 3 f16 transposed
// [n][m] (+bias), ldc = transposed pitch.
template<int WM, int WN, int EPI, bool QK>
__global__ __launch_bounds__(256) void gemm_nt(
    const f16_t* __restrict__ Ah, const f16_t* __restrict__ Bh,
    void* __restrict__ Cout0,
    const float* __restrict__ bias, const float* __restrict__ resid,
    int K, int ldc,
    long sAz, long sBz, long sCz, long sRz, long sAw, long sBw, long sCw)
{
    constexpr int BM = 2 * WM * 16;
    constexpr int BN = 2 * WN * 16;
    constexpr int BK = 32;
    __shared__ __align__(16) f16_t smem[(BM + BN) * BK];
    f16_t* sA = smem;
    f16_t* sB = smem + BM * BK;

    const int tid  = threadIdx.x;
    const int wave = tid >> 6, lane = tid & 63;
    const int wm = (wave >> 1) * (WM * 16);
    const int wn = (wave & 1) * (WN * 16);
    const int fr = lane & 15;
    const int fk = (lane >> 4) * 8;
    const int srow = lane >> 2;          // row within 16-row staging segment
    const int scol = (lane & 3) * 8;     // elem offset within row (16B)

    const long mBlock = (long)blockIdx.y * BM;
    const long nBlock = (long)blockIdx.x * BN;
    const int zz = blockIdx.z;
    const int z   = QK ? (zz & 3) : zz;
    const int sel = QK ? (zz >> 2) : 0;
    const f16_t* Az = Ah + (size_t)z * sAz + (size_t)sel * sAw;
    const f16_t* Bz = Bh + (size_t)z * sBz + (size_t)sel * sBw;
    const float* biasp = bias ? (bias + (QK ? sel * C_DIM : 0)) : nullptr;

    const f16_t* gA = Az + (size_t)(mBlock + srow) * K + scol;
    const f16_t* gB = Bz + (size_t)(nBlock + srow) * K + scol;

    f32x4 acc[WM][WN];
#pragma unroll
    for (int i = 0; i < WM; i++)
#pragma unroll
        for (int j = 0; j < WN; j++)
            acc[i][j] = (f32x4){0.f, 0.f, 0.f, 0.f};

    for (int k0 = 0; k0 < K; k0 += BK) {
        __syncthreads();
#pragma unroll
        for (int s = 0; s < BM / 16; s += 4) {
            int seg = s + wave;
            g2l16(gA + (size_t)seg * 16 * K + k0, sA + seg * 512);
        }
#pragma unroll
        for (int s = 0; s < BN / 16; s += 4) {
            int seg = s + wave;
            g2l16(gB + (size_t)seg * 16 * K + k0, sB + seg * 512);
        }
        __syncthreads();

        f16x8 af[WM], bf[WN];
#pragma unroll
        for (int i = 0; i < WM; i++)
            af[i] = *reinterpret_cast<const f16x8*>(sA + (wm + i * 16 + fr) * BK + fk);
#pragma unroll
        for (int j = 0; j < WN; j++)
            bf[j] = *reinterpret_cast<const f16x8*>(sB + (wn + j * 16 + fr) * BK + fk);
#pragma unroll
        for (int i = 0; i < WM; i++)
#pragma unroll
            for (int j = 0; j < WN; j++)
                acc[i][j] = mfma_f16(af[i], bf[j], acc[i][j]);
    }

    // epilogue. D layout: col(n)=lane&15, row(m)=(lane>>4)*4+reg
    const int col  = lane & 15;
    const int rowq = (lane >> 4) * 4;
    const size_t cbase = (size_t)z * sCz + (size_t)sel * sCw;
#pragma unroll
    for (int i = 0; i < WM; i++) {
        const long mb = mBlock + wm + i * 16 + rowq;
        float bv[4];
#pragma unroll
        for (int r = 0; r < 4; r++) bv[r] = biasp ? biasp[mb + r] : 0.0f;
#pragma unroll
        for (int j = 0; j < WN; j++) {
            const long n = nBlock + wn + j * 16 + col;
            float v[4];
#pragma unroll
            for (int r = 0; r < 4; r++) v[r] = acc[i][j][r] + bv[r];
            if constexpr (EPI == 0) {
                float* O = (float*)Cout0 + cbase;
                const float* R = resid ? (resid + (size_t)z * sRz) : nullptr;
#pragma unroll
                for (int r = 0; r < 4; r++) {
                    size_t off = (size_t)(mb + r) * ldc + n;
                    O[off] = v[r] + (R ? R[off] : 0.0f);
                }
            } else if constexpr (EPI == 1) {
                f16_t* O = (f16_t*)Cout0 + cbase;
#pragma unroll
                for (int r = 0; r < 4; r++) O[(size_t)(mb + r) * ldc + n] = (f16_t)v[r];
            } else {
                alignas(8) f16_t h[4];
#pragma unroll
                for (int r = 0; r < 4; r++) h[r] = (f16_t)v[r];
                size_t offo = cbase + (size_t)n * ldc + mb;
                *reinterpret_cast<uint2*>((f16_t*)Cout0 + offo) = *reinterpret_cast<uint2*>(h);
            }
        }
    }
}

// ---------------------------------------------------------------------------
extern "C" void kernel_launch(void* const* d_in, const int* in_sizes, int n_in,
                              void* d_out, int out_size, void* d_ws, size_t ws_size,
                              hipStream_t stream)
{
    const float* x_fcc = (const float*)d_in[0];
    const float* x_fss = (const float*)d_in[1];
    const float* w1 = (const float*)d_in[2];
    const float* b1 = (const float*)d_in[3];
    const float* w2 = (const float*)d_in[4];
    const float* b2 = (const float*)d_in[5];
    const float* w3 = (const float*)d_in[6];
    const float* b3 = (const float*)d_in[7];
    const float* wrs = (const float*)d_in[8];
    const float* brs = (const float*)d_in[9];
    float* out = (float*)d_out;
    (void)n_in; (void)in_sizes; (void)out_size; (void)ws_size;

    char* base = (char*)d_ws;
    size_t off = 0;
    auto take = [&](size_t bytes) -> char* {
        char* p = base + off;
        off += (bytes + 255) & ~(size_t)255;
        return p;
    };
    const size_t WB = (size_t)C_DIM * C_DIM * sizeof(f16_t);    // 512 KB
    const size_t TB = (size_t)NBATCH * CHW * sizeof(f16_t);     // 16 MB
    const long  TBe = NBATCH * CHW;                             // 8388608 elems

    float* meanc = (float*)take(2048 * 4);
    float* rstdc = (float*)take(2048 * 4);
    float* means = (float*)take(2048 * 4);
    float* rstds = (float*)take(2048 * 4);
    float* biasws = (float*)take(4 * C_DIM * 4);
    // weights contiguous: w1h -> w2h sel stride = C_DIM*C_DIM elems (512 KB,
    // 256-aligned so take() keeps them exactly adjacent)
    f16_t* w1h = (f16_t*)take(WB);
    f16_t* w2h = (f16_t*)take(WB);
    f16_t* w3h = (f16_t*)take(WB);
    f16_t* wrh = (f16_t*)take(WB);
    // qT -> kT adjacent: C sel stride = TBe elems
    f16_t* qT = (f16_t*)take(TB);
    f16_t* kT = (f16_t*)take(TB);
    f16_t* vh   = (f16_t*)take(TB);
    f16_t* frsT = (f16_t*)take(TB);
    // 96 MB region: phase-1 packed inputs xcT(16) xsT(16) xsrT(16);
    // phase-2: S fp32 [0,64) MB (packs dead by then), P fp16 [64,96) MB.
    char* packb = take(6 * TB);
    f16_t* xcT  = (f16_t*)(packb);
    f16_t* xsT  = (f16_t*)(packb + TB);
    f16_t* xsrT = (f16_t*)(packb + 2 * TB);
    float* Smat = (float*)(packb);
    f16_t* Pmat = (f16_t*)(packb + 4 * TB);

    dim3 blk(256);

    // 1. stats
    stats_kernel<<<dim3(4096), blk, 0, stream>>>(x_fcc, x_fss, meanc, rstdc, means, rstds);
    // 2. weight packs + bias copy
    pack_w4_kernel<<<dim3(1024, 4), blk, 0, stream>>>(
        w1, w2, w3, wrs, w1h, w2h, w3h, wrh, b1, b2, b3, brs, biasws);
    // 3. input packs (content norm, style norm, style raw)
    pack_T_kernel<<<dim3(128, 16, 12), blk, 0, stream>>>(
        x_fcc, x_fss, meanc, rstdc, means, rstds, xcT, xsT, xsrT);
    // 4. q+k convs merged: sel 0 = (w1, content)->qT; sel 1 = (w2, style)->kT
    gemm_nt<4, 4, 3, true><<<dim3(32, 4, 8), blk, 0, stream>>>(
        w1h, xcT, qT, biasws, nullptr, C_DIM, C_DIM,
        0L, CHW, CHW, 0L, (long)C_DIM * C_DIM, TBe, TBe);
    // 5. v conv: [c][p] layout
    gemm_nt<4, 4, 1, false><<<dim3(32, 4, 4), blk, 0, stream>>>(
        w3h, xsrT, vh, biasws + 2 * C_DIM, nullptr, C_DIM, HW_DIM,
        0L, CHW, CHW, 0L, 0L, 0L, 0L);
    // 6. per-batch attention (S/P L3-hot between stages)
    for (int b = 0; b < NBATCH; b++) {
        gemm_nt<4, 4, 0, false><<<dim3(32, 32, 1), blk, 0, stream>>>(
            qT + (size_t)b * CHW, kT + (size_t)b * CHW,
            Smat, nullptr, nullptr, C_DIM, HW_DIM,
            0L, 0L, 0L, 0L, 0L, 0L, 0L);
        softmax_rows<<<dim3(4096), blk, 0, stream>>>(Smat, Pmat);
        gemm_nt<2, 4, 3, false><<<dim3(32, 8, 1), blk, 0, stream>>>(
            vh + (size_t)b * CHW, Pmat,
            frsT + (size_t)b * CHW, nullptr, nullptr, HW_DIM, C_DIM,
            0L, 0L, 0L, 0L, 0L, 0L, 0L);
    }
    // 7. final conv + bias + residual -> fp32 out
    gemm_nt<4, 4, 0, false><<<dim3(32, 4, 4), blk, 0, stream>>>(
        wrh, frsT, out, biasws + 3 * C_DIM, x_fcc, C_DIM, HW_DIM,
        0L, CHW, CHW, CHW, 0L, 0L, 0L);
}

// Round 6
// 648.652 us; speedup vs baseline: 1.3888x; 1.1384x over previous
//
#include <hip/hip_runtime.h>
#include <hip/hip_bf16.h>

// SA_fusion: B=4, C=512, H=W=64 (HW=4096), fp32 in/out.
// R6: split-K PV. R5's PV was 4x71us with 256 blocks (1/CU), MfmaUtil 8.6% --
// pure latency bound (128 barrier-drained K-iters, nothing co-resident to
// hide them). Split K=4096 into 4 chunks -> (32,8,4)=1024 blocks (4/CU),
// fp32 partials [q][c] + vectorized reduce -> fp16 frsT.
// Workspace ~194 MB (<= R2's known-good 196 MB).

typedef _Float16 f16_t;
typedef _Float16 f16x8 __attribute__((ext_vector_type(8)));
typedef float f32x4 __attribute__((ext_vector_type(4)));

#define C_DIM 512
#define HW_DIM 4096
#define NBATCH 4
#define CHW (512L * 4096L)
#define HWHW (4096L * 4096L)

__device__ inline f32x4 mfma_f16(f16x8 a, f16x8 b, f32x4 c) {
    return __builtin_amdgcn_mfma_f32_16x16x32_f16(a, b, c, 0, 0, 0);
}

// async 16B/lane global->LDS; lane i lands at base + i*16 (wave-uniform base).
__device__ inline void g2l16(const f16_t* g, f16_t* l) {
    auto gp = (const __attribute__((address_space(1))) uint32_t*)(uintptr_t)g;
    auto lp = (__attribute__((address_space(3))) uint32_t*)(uint32_t)(uintptr_t)l;
    __builtin_amdgcn_global_load_lds(gp, lp, 16, 0, 0);
}

// ---------------- stats: mean + rstd (unbiased var, ddof=1) per (b,c) --------
__global__ __launch_bounds__(256) void stats_kernel(
    const float* __restrict__ xc, const float* __restrict__ xs,
    float* __restrict__ meanc, float* __restrict__ rstdc,
    float* __restrict__ means, float* __restrict__ rstds)
{
    int id = blockIdx.x;
    int bc = id & 2047;
    const float4* x = (const float4*)((id < 2048 ? xc : xs) + (size_t)bc * HW_DIM);
    int tid = threadIdx.x;
    float s = 0.f, ss = 0.f;
#pragma unroll
    for (int i = 0; i < 4; i++) {
        float4 v = x[tid + (i << 8)];
        s += v.x + v.y + v.z + v.w;
        ss += v.x * v.x + v.y * v.y + v.z * v.z + v.w * v.w;
    }
#pragma unroll
    for (int o = 32; o; o >>= 1) { s += __shfl_down(s, o); ss += __shfl_down(ss, o); }
    __shared__ float red[8];
    if ((tid & 63) == 0) { red[(tid >> 6) * 2] = s; red[(tid >> 6) * 2 + 1] = ss; }
    __syncthreads();
    if (tid == 0) {
        s  = red[0] + red[2] + red[4] + red[6];
        ss = red[1] + red[3] + red[5] + red[7];
        float mean = s * (1.0f / 4096.0f);
        float var  = (ss - 4096.0f * mean * mean) * (1.0f / 4095.0f);
        float rstd = rsqrtf(var + 1e-5f);
        if (id < 2048) { meanc[bc] = mean; rstdc[bc] = rstd; }
        else           { means[bc] = mean; rstds[bc] = rstd; }
    }
}

// ---------------- weight pack: fp32 -> fp16 + bias copy ----------------------
__global__ __launch_bounds__(256) void pack_w4_kernel(
    const float* __restrict__ w0, const float* __restrict__ w1,
    const float* __restrict__ w2, const float* __restrict__ w3,
    f16_t* __restrict__ h0, f16_t* __restrict__ h1,
    f16_t* __restrict__ h2, f16_t* __restrict__ h3,
    const float* __restrict__ bb0, const float* __restrict__ bb1,
    const float* __restrict__ bb2, const float* __restrict__ bb3,
    float* __restrict__ biasws)
{
    int which = blockIdx.y;
    const float* w = which == 0 ? w0 : which == 1 ? w1 : which == 2 ? w2 : w3;
    f16_t* h = which == 0 ? h0 : which == 1 ? h1 : which == 2 ? h2 : h3;
    const float* bs = which == 0 ? bb0 : which == 1 ? bb1 : which == 2 ? bb2 : bb3;
    int i = blockIdx.x * 256 + threadIdx.x;
    h[i] = (f16_t)w[i];
    if (i < C_DIM) biasws[which * C_DIM + i] = bs[i];
}

// ---------------- input pack: (B,C,HW) fp32 -> (B,HW,C) fp16, opt norm -------
__global__ __launch_bounds__(256) void pack_T_kernel(
    const float* __restrict__ xc, const float* __restrict__ xs,
    const float* __restrict__ meanc, const float* __restrict__ rstdc,
    const float* __restrict__ means, const float* __restrict__ rstds,
    f16_t* __restrict__ ch, f16_t* __restrict__ sh, f16_t* __restrict__ sraw)
{
    __shared__ float tile[32][33];
    int z = blockIdx.z;
    int b = z & 3, src = z >> 2;
    const float* x    = (src == 0) ? xc : xs;
    const float* mean = (src == 0) ? meanc : means;
    const float* rstd = (src == 0) ? rstdc : rstds;
    f16_t* oh = (src == 0) ? ch : (src == 1) ? sh : sraw;
    bool norm = (src < 2);

    int c0 = blockIdx.y * 32, p0 = blockIdx.x * 32;
    int tp = threadIdx.x & 31, tc8 = threadIdx.x >> 5;
    const float* xb = x + ((size_t)b * C_DIM + c0) * HW_DIM + p0;
#pragma unroll
    for (int it = 0; it < 4; it++) {
        int c = tc8 + it * 8;
        float v = xb[(size_t)c * HW_DIM + tp];
        if (norm) {
            float m = mean[b * C_DIM + c0 + c];
            float r = rstd[b * C_DIM + c0 + c];
            v = (v - m) * r;
        }
        tile[c][tp] = v;
    }
    __syncthreads();
    int wc = threadIdx.x & 31, wp8 = threadIdx.x >> 5;
    f16_t* ohb = oh + ((size_t)b * HW_DIM + p0) * C_DIM + c0;
#pragma unroll
    for (int it = 0; it < 4; it++) {
        int p = wp8 + it * 8;
        ohb[(size_t)p * C_DIM + wc] = (f16_t)tile[wc][p];
    }
}

// ---------------- row softmax: S fp32 (4096x4096) -> P fp16, normalized ------
__global__ __launch_bounds__(256) void softmax_rows(
    const float* __restrict__ S, f16_t* __restrict__ P)
{
    int row = blockIdx.x;
    int tid = threadIdx.x;
    int wave = tid >> 6, lane = tid & 63;
    const float4* sr = (const float4*)(S + (size_t)row * HW_DIM);
    float4 v[4];
    float mx = -3.4e38f;
#pragma unroll
    for (int i = 0; i < 4; i++) {
        v[i] = sr[tid + (i << 8)];
        mx = fmaxf(mx, fmaxf(fmaxf(v[i].x, v[i].y), fmaxf(v[i].z, v[i].w)));
    }
#pragma unroll
    for (int o = 32; o; o >>= 1) mx = fmaxf(mx, __shfl_down(mx, o));
    __shared__ float red[4];
    if (lane == 0) red[wave] = mx;
    __syncthreads();
    mx = fmaxf(fmaxf(red[0], red[1]), fmaxf(red[2], red[3]));
    float sum = 0.f;
#pragma unroll
    for (int i = 0; i < 4; i++) {
        v[i].x = __expf(v[i].x - mx); v[i].y = __expf(v[i].y - mx);
        v[i].z = __expf(v[i].z - mx); v[i].w = __expf(v[i].w - mx);
        sum += v[i].x + v[i].y + v[i].z + v[i].w;
    }
#pragma unroll
    for (int o = 32; o; o >>= 1) sum += __shfl_down(sum, o);
    __syncthreads();
    if (lane == 0) red[wave] = sum;
    __syncthreads();
    sum = red[0] + red[1] + red[2] + red[3];
    float inv = 1.0f / sum;
    uint2* pr = (uint2*)(P + (size_t)row * HW_DIM);
#pragma unroll
    for (int i = 0; i < 4; i++) {
        union { uint2 u; f16_t h[4]; } o;
        o.h[0] = (f16_t)(v[i].x * inv); o.h[1] = (f16_t)(v[i].y * inv);
        o.h[2] = (f16_t)(v[i].z * inv); o.h[3] = (f16_t)(v[i].w * inv);
        pr[tid + (i << 8)] = o.u;
    }
}

// ---------------- split-K reduce: frsT[q][c] = f16(sum of 4 fp32 partials) ---
__global__ __launch_bounds__(256) void reduce4_kernel(
    const float* __restrict__ part, f16_t* __restrict__ out)
{
    size_t i = (size_t)blockIdx.x * 256 + threadIdx.x;   // float4 index
    const float4* p0 = (const float4*)part;
    const float4* p1 = (const float4*)(part + CHW);
    const float4* p2 = (const float4*)(part + 2 * CHW);
    const float4* p3 = (const float4*)(part + 3 * CHW);
    float4 a = p0[i], b = p1[i], c = p2[i], d = p3[i];
    union { uint2 u; f16_t h[4]; } o;
    o.h[0] = (f16_t)(a.x + b.x + c.x + d.x);
    o.h[1] = (f16_t)(a.y + b.y + c.y + d.y);
    o.h[2] = (f16_t)(a.z + b.z + c.z + d.z);
    o.h[3] = (f16_t)(a.w + b.w + c.w + d.w);
    ((uint2*)out)[i] = o.u;
}

// ---------------- NT GEMM: C[m][n] = sum_k A[m][k]*B[n][k] -------------------
// fp16, 16x16x32 MFMA, block=256 (2x2 waves), async global_load_lds staging,
// unpadded [row][32] LDS tiles. lda = row pitch of A and B (may exceed loop K
// for split-K). QK: z encodes (sel=z>>2, batch=z&3); sel strides A(sAw),
// B(sBw), bias(+sel*C_DIM), C(sCw).
// EPI: 0 fp32 [m][n] (+bias,+resid); 1 f16 [m][n] (+bias);
//      3 f16 transposed [n][m] (+bias); 4 fp32 transposed [n][m] (no bias).
template<int WM, int WN, int EPI, bool QK>
__global__ __launch_bounds__(256) void gemm_nt(
    const f16_t* __restrict__ Ah, const f16_t* __restrict__ Bh,
    void* __restrict__ Cout0,
    const float* __restrict__ bias, const float* __restrict__ resid,
    int K, int lda, int ldc,
    long sAz, long sBz, long sCz, long sRz, long sAw, long sBw, long sCw)
{
    constexpr int BM = 2 * WM * 16;
    constexpr int BN = 2 * WN * 16;
    constexpr int BK = 32;
    __shared__ __align__(16) f16_t smem[(BM + BN) * BK];
    f16_t* sA = smem;
    f16_t* sB = smem + BM * BK;

    const int tid  = threadIdx.x;
    const int wave = tid >> 6, lane = tid & 63;
    const int wm = (wave >> 1) * (WM * 16);
    const int wn = (wave & 1) * (WN * 16);
    const int fr = lane & 15;
    const int fk = (lane >> 4) * 8;
    const int srow = lane >> 2;          // row within 16-row staging segment
    const int scol = (lane & 3) * 8;     // elem offset within row (16B)

    const long mBlock = (long)blockIdx.y * BM;
    const long nBlock = (long)blockIdx.x * BN;
    const int zz = blockIdx.z;
    const int z   = QK ? (zz & 3) : zz;
    const int sel = QK ? (zz >> 2) : 0;
    const f16_t* Az = Ah + (size_t)z * sAz + (size_t)sel * sAw;
    const f16_t* Bz = Bh + (size_t)z * sBz + (size_t)sel * sBw;
    const float* biasp = bias ? (bias + (QK ? sel * C_DIM : 0)) : nullptr;

    const f16_t* gA = Az + (size_t)(mBlock + srow) * lda + scol;
    const f16_t* gB = Bz + (size_t)(nBlock + srow) * lda + scol;

    f32x4 acc[WM][WN];
#pragma unroll
    for (int i = 0; i < WM; i++)
#pragma unroll
        for (int j = 0; j < WN; j++)
            acc[i][j] = (f32x4){0.f, 0.f, 0.f, 0.f};

    for (int k0 = 0; k0 < K; k0 += BK) {
        __syncthreads();
#pragma unroll
        for (int s = 0; s < BM / 16; s += 4) {
            int seg = s + wave;
            g2l16(gA + (size_t)seg * 16 * lda + k0, sA + seg * 512);
        }
#pragma unroll
        for (int s = 0; s < BN / 16; s += 4) {
            int seg = s + wave;
            g2l16(gB + (size_t)seg * 16 * lda + k0, sB + seg * 512);
        }
        __syncthreads();

        f16x8 af[WM], bf[WN];
#pragma unroll
        for (int i = 0; i < WM; i++)
            af[i] = *reinterpret_cast<const f16x8*>(sA + (wm + i * 16 + fr) * BK + fk);
#pragma unroll
        for (int j = 0; j < WN; j++)
            bf[j] = *reinterpret_cast<const f16x8*>(sB + (wn + j * 16 + fr) * BK + fk);
#pragma unroll
        for (int i = 0; i < WM; i++)
#pragma unroll
            for (int j = 0; j < WN; j++)
                acc[i][j] = mfma_f16(af[i], bf[j], acc[i][j]);
    }

    // epilogue. D layout: col(n)=lane&15, row(m)=(lane>>4)*4+reg
    const int col  = lane & 15;
    const int rowq = (lane >> 4) * 4;
    const size_t cbase = (size_t)z * sCz + (size_t)sel * sCw;
#pragma unroll
    for (int i = 0; i < WM; i++) {
        const long mb = mBlock + wm + i * 16 + rowq;
        float bv[4];
#pragma unroll
        for (int r = 0; r < 4; r++) bv[r] = biasp ? biasp[mb + r] : 0.0f;
#pragma unroll
        for (int j = 0; j < WN; j++) {
            const long n = nBlock + wn + j * 16 + col;
            float v[4];
#pragma unroll
            for (int r = 0; r < 4; r++) v[r] = acc[i][j][r] + bv[r];
            if constexpr (EPI == 0) {
                float* O = (float*)Cout0 + cbase;
                const float* R = resid ? (resid + (size_t)z * sRz) : nullptr;
#pragma unroll
                for (int r = 0; r < 4; r++) {
                    size_t off = (size_t)(mb + r) * ldc + n;
                    O[off] = v[r] + (R ? R[off] : 0.0f);
                }
            } else if constexpr (EPI == 1) {
                f16_t* O = (f16_t*)Cout0 + cbase;
#pragma unroll
                for (int r = 0; r < 4; r++) O[(size_t)(mb + r) * ldc + n] = (f16_t)v[r];
            } else if constexpr (EPI == 3) {
                alignas(8) f16_t h[4];
#pragma unroll
                for (int r = 0; r < 4; r++) h[r] = (f16_t)v[r];
                size_t offo = cbase + (size_t)n * ldc + mb;
                *reinterpret_cast<uint2*>((f16_t*)Cout0 + offo) = *reinterpret_cast<uint2*>(h);
            } else {   // EPI == 4: fp32 transposed partial
                alignas(16) float h[4];
#pragma unroll
                for (int r = 0; r < 4; r++) h[r] = v[r];
                size_t offo = cbase + (size_t)n * ldc + mb;
                *reinterpret_cast<float4*>((float*)Cout0 + offo) = *reinterpret_cast<float4*>(h);
            }
        }
    }
}

// ---------------------------------------------------------------------------
extern "C" void kernel_launch(void* const* d_in, const int* in_sizes, int n_in,
                              void* d_out, int out_size, void* d_ws, size_t ws_size,
                              hipStream_t stream)
{
    const float* x_fcc = (const float*)d_in[0];
    const float* x_fss = (const float*)d_in[1];
    const float* w1 = (const float*)d_in[2];
    const float* b1 = (const float*)d_in[3];
    const float* w2 = (const float*)d_in[4];
    const float* b2 = (const float*)d_in[5];
    const float* w3 = (const float*)d_in[6];
    const float* b3 = (const float*)d_in[7];
    const float* wrs = (const float*)d_in[8];
    const float* brs = (const float*)d_in[9];
    float* out = (float*)d_out;
    (void)n_in; (void)in_sizes; (void)out_size; (void)ws_size;

    char* base = (char*)d_ws;
    size_t off = 0;
    auto take = [&](size_t bytes) -> char* {
        char* p = base + off;
        off += (bytes + 255) & ~(size_t)255;
        return p;
    };
    const size_t WB = (size_t)C_DIM * C_DIM * sizeof(f16_t);    // 512 KB
    const size_t TB = (size_t)NBATCH * CHW * sizeof(f16_t);     // 16 MB
    const long  TBe = NBATCH * CHW;                             // 8388608 elems

    float* meanc = (float*)take(2048 * 4);
    float* rstdc = (float*)take(2048 * 4);
    float* means = (float*)take(2048 * 4);
    float* rstds = (float*)take(2048 * 4);
    float* biasws = (float*)take(4 * C_DIM * 4);
    // weights contiguous: w1h -> w2h sel stride = C_DIM*C_DIM elems
    f16_t* w1h = (f16_t*)take(WB);
    f16_t* w2h = (f16_t*)take(WB);
    f16_t* w3h = (f16_t*)take(WB);
    f16_t* wrh = (f16_t*)take(WB);
    // qT -> kT adjacent: C sel stride = TBe elems
    f16_t* qT = (f16_t*)take(TB);
    f16_t* kT = (f16_t*)take(TB);
    f16_t* vh   = (f16_t*)take(TB);
    f16_t* frsT = (f16_t*)take(TB);
    // 128 MB region: phase-1 packs xcT(16) xsT(16) xsrT(16) [dead after convs]
    // phase-2: S fp32 [0,64), P fp16 [64,96), split-K partials fp32 [96,128)
    char* packb = take(8 * TB);
    f16_t* xcT  = (f16_t*)(packb);
    f16_t* xsT  = (f16_t*)(packb + TB);
    f16_t* xsrT = (f16_t*)(packb + 2 * TB);
    float* Smat = (float*)(packb);
    f16_t* Pmat = (f16_t*)(packb + 4 * TB);
    float* Part = (float*)(packb + 6 * TB);
    // total ws: ~0.05 + 2 + 64 + 128 = ~194 MB (<= R2's proven 196 MB)

    dim3 blk(256);

    // 1. stats
    stats_kernel<<<dim3(4096), blk, 0, stream>>>(x_fcc, x_fss, meanc, rstdc, means, rstds);
    // 2. weight packs + bias copy
    pack_w4_kernel<<<dim3(1024, 4), blk, 0, stream>>>(
        w1, w2, w3, wrs, w1h, w2h, w3h, wrh, b1, b2, b3, brs, biasws);
    // 3. input packs (content norm, style norm, style raw)
    pack_T_kernel<<<dim3(128, 16, 12), blk, 0, stream>>>(
        x_fcc, x_fss, meanc, rstdc, means, rstds, xcT, xsT, xsrT);
    // 4. q+k convs merged: sel 0 = (w1, content)->qT; sel 1 = (w2, style)->kT
    gemm_nt<4, 4, 3, true><<<dim3(32, 4, 8), blk, 0, stream>>>(
        w1h, xcT, qT, biasws, nullptr, C_DIM, C_DIM, C_DIM,
        0L, CHW, CHW, 0L, (long)C_DIM * C_DIM, TBe, TBe);
    // 5. v conv: [c][p] layout
    gemm_nt<4, 4, 1, false><<<dim3(32, 4, 4), blk, 0, stream>>>(
        w3h, xsrT, vh, biasws + 2 * C_DIM, nullptr, C_DIM, C_DIM, HW_DIM,
        0L, CHW, CHW, 0L, 0L, 0L, 0L);
    // 6. per-batch attention
    for (int b = 0; b < NBATCH; b++) {
        // scores: S[q][k] = q . k  (1024 blocks, 4/CU)
        gemm_nt<4, 4, 0, false><<<dim3(32, 32, 1), blk, 0, stream>>>(
            qT + (size_t)b * CHW, kT + (size_t)b * CHW,
            Smat, nullptr, nullptr, C_DIM, C_DIM, HW_DIM,
            0L, 0L, 0L, 0L, 0L, 0L, 0L);
        softmax_rows<<<dim3(4096), blk, 0, stream>>>(Smat, Pmat);
        // PV split-K: z = split (k-offset z*1024), partial[z] fp32 [q][c]
        gemm_nt<2, 4, 4, false><<<dim3(32, 8, 4), blk, 0, stream>>>(
            vh + (size_t)b * CHW, Pmat,
            Part, nullptr, nullptr, 1024, HW_DIM, C_DIM,
            1024L, 1024L, CHW, 0L, 0L, 0L, 0L);
        // reduce 4 partials -> fp16 frsT[b]  (2048 blocks)
        reduce4_kernel<<<dim3(CHW / 1024), blk, 0, stream>>>(
            Part, frsT + (size_t)b * CHW);
    }
    // 7. final conv + bias + residual -> fp32 out
    gemm_nt<4, 4, 0, false><<<dim3(32, 4, 4), blk, 0, stream>>>(
        wrh, frsT, out, biasws + 3 * C_DIM, x_fcc, C_DIM, C_DIM, HW_DIM,
        0L, CHW, CHW, CHW, 0L, 0L, 0L);
}